// Round 18
// baseline (79.245 us; speedup 1.0000x reference)
//
#include <hip/hip_runtime.h>
#include <hip/hip_bf16.h>
#include <stdint.h>

typedef __attribute__((ext_vector_type(8))) short short8;
typedef __attribute__((ext_vector_type(4))) float f32x4;
typedef __attribute__((ext_vector_type(16))) float f32x16;
typedef __attribute__((ext_vector_type(4))) int i32x4;
typedef __attribute__((ext_vector_type(8))) int i32x8;

#define N_PTS 8192
#define M_PTS 8192
#define DIM   512
#define KDIM  128

// ---- float <-> order-preserving uint key (for atomicMin on float) ----
__device__ __forceinline__ unsigned fenc(float f) {
  unsigned u = __float_as_uint(f);
  return (u & 0x80000000u) ? ~u : (u | 0x80000000u);
}
__device__ __forceinline__ float fdec(unsigned k) {
  unsigned u = (k & 0x80000000u) ? (k ^ 0x80000000u) : ~k;
  return __uint_as_float(u);
}

__device__ __forceinline__ unsigned short f2bf(float f) {
  union { __hip_bfloat16 h; unsigned short u; } c;
  c.h = __float2bfloat16(f);
  return c.u;
}

// ---- float -> OCP e4m3fn, RNE, flush |f|<2^-6 to 0 (x,t ~ N(0,1)) ----
__device__ __forceinline__ unsigned f2e4m3(float f) {
  unsigned u = __float_as_uint(f);
  unsigned s = (u >> 24) & 0x80;
  unsigned mag = u & 0x7fffffffu;
  unsigned r = mag + 0x0007ffffu + ((mag >> 20) & 1u);  // RNE to 3 mantissa bits
  int e = (int)(r >> 23) - 127;
  if (e < -6) return s;                                 // flush tiny to zero
  unsigned m = (r >> 20) & 7u;
  return s | (unsigned)((e + 7) << 3) | m;
}

// ---- async global -> LDS, 16B per lane (phi_b kernel only) ----
__device__ __forceinline__ void async_copy16(const void* g, void* l) {
  __builtin_amdgcn_global_load_lds(
      (const __attribute__((address_space(1))) void*)g,
      (__attribute__((address_space(3))) void*)l, 16, 0, 0);
}

// ---- bf16 LDS slot swizzle (phi_b kernel, verified 0 conflicts) ----
__device__ __forceinline__ int swz_slot(int row, int slot) {
  return slot ^ ((row >> 1) & 3);
}

// =====================================================================
// Kernel 1: prep-all. Blocks < 4096: one wave per row:
// x -> Xb(bf16) + XfT(e4m3 FRAGMENT-MAJOR [kt][8192][64B]) + xsq;
// target -> TfT (same frag-major) + tsq + key init.
// Blocks >= 4096: W [D][K] fp32 -> WbT [K][D] bf16 transpose-cast.
// =====================================================================
__global__ __launch_bounds__(256)
void prep_all_kernel(const float* __restrict__ x, const float* __restrict__ tgt,
                     const float* __restrict__ W,
                     unsigned short* __restrict__ Xb, unsigned char* __restrict__ XfT,
                     unsigned char* __restrict__ TfT, unsigned short* __restrict__ WbT,
                     float* __restrict__ xsq, float* __restrict__ tsq,
                     unsigned* __restrict__ keys) {
  const int bid = blockIdx.x;
  const int tid = threadIdx.x;
  if (bid >= (N_PTS + M_PTS) / 4) {
    const int o = (bid - (N_PTS + M_PTS) / 4) * 256 + tid;  // 0..65535
    const int k = o >> 9, d = o & 511;
    WbT[o] = f2bf(W[d * KDIM + k]);
    return;
  }
  const int gw = (bid * 256 + tid) >> 6;
  const int j = tid & 63;
  float s;
  if (gw < N_PTS) {
    const float* src = x + (size_t)gw * DIM + j * 8;
    float4 v0 = *(const float4*)src;
    float4 v1 = *(const float4*)(src + 4);
    s = v0.x * v0.x + v0.y * v0.y + v0.z * v0.z + v0.w * v0.w +
        v1.x * v1.x + v1.y * v1.y + v1.z * v1.z + v1.w * v1.w;
    unsigned short* db = Xb + (size_t)gw * DIM + j * 8;
    ushort4 ob0, ob1;
    ob0.x = f2bf(v0.x); ob0.y = f2bf(v0.y); ob0.z = f2bf(v0.z); ob0.w = f2bf(v0.w);
    ob1.x = f2bf(v1.x); ob1.y = f2bf(v1.y); ob1.z = f2bf(v1.z); ob1.w = f2bf(v1.w);
    *(ushort4*)db = ob0;
    *(ushort4*)(db + 4) = ob1;
    unsigned long long p = (unsigned long long)f2e4m3(v0.x)
        | ((unsigned long long)f2e4m3(v0.y) << 8)
        | ((unsigned long long)f2e4m3(v0.z) << 16)
        | ((unsigned long long)f2e4m3(v0.w) << 24)
        | ((unsigned long long)f2e4m3(v1.x) << 32)
        | ((unsigned long long)f2e4m3(v1.y) << 40)
        | ((unsigned long long)f2e4m3(v1.z) << 48)
        | ((unsigned long long)f2e4m3(v1.w) << 56);
    // fragment-major: [kt = j>>3][row gw][byte (j&7)*8]
    *(unsigned long long*)(XfT + ((size_t)(j >> 3) * N_PTS + gw) * 64 + (j & 7) * 8) = p;
#pragma unroll
    for (int m = 1; m <= 32; m <<= 1) s += __shfl_xor(s, m);
    if (j == 0) xsq[gw] = s;
  } else {
    const int tr = gw - N_PTS;
    const float* src = tgt + (size_t)tr * DIM + j * 8;
    float4 v0 = *(const float4*)src;
    float4 v1 = *(const float4*)(src + 4);
    s = v0.x * v0.x + v0.y * v0.y + v0.z * v0.z + v0.w * v0.w +
        v1.x * v1.x + v1.y * v1.y + v1.z * v1.z + v1.w * v1.w;
    unsigned long long p = (unsigned long long)f2e4m3(v0.x)
        | ((unsigned long long)f2e4m3(v0.y) << 8)
        | ((unsigned long long)f2e4m3(v0.z) << 16)
        | ((unsigned long long)f2e4m3(v0.w) << 24)
        | ((unsigned long long)f2e4m3(v1.x) << 32)
        | ((unsigned long long)f2e4m3(v1.y) << 40)
        | ((unsigned long long)f2e4m3(v1.z) << 48)
        | ((unsigned long long)f2e4m3(v1.w) << 56);
    *(unsigned long long*)(TfT + ((size_t)(j >> 3) * M_PTS + tr) * 64 + (j & 7) * 8) = p;
#pragma unroll
    for (int m = 1; m <= 32; m <<= 1) s += __shfl_xor(s, m);
    if (j == 0) { tsq[tr] = s; keys[tr] = 0xFFFFFFFFu; }
  }
}

// =====================================================================
// Kernel 2: phi_b — 256 blocks x 32 rows (r16 retile, unchanged).
// =====================================================================
__global__ __launch_bounds__(256)
void phi_b_kernel(const short* __restrict__ Xb, const short* __restrict__ WbT,
                  float* __restrict__ phi_b) {
  __shared__ __align__(16) short As[32 * 32];
  __shared__ __align__(16) short Bs[128 * 32];
  __shared__ __align__(16) float lg[32][136];

  const int tid = threadIdx.x;
  const int wave = tid >> 6, lane = tid & 63;
  const int n0 = blockIdx.x * 32;
  const int fr = lane & 15, g = lane >> 4;
  const int wc = wave;

  const int srow = tid >> 2;
  const int sk8 = swz_slot(srow, tid & 3) * 8;
  const int ra = tid >> 2;
  const int ska = swz_slot(ra, tid & 3) * 8;

  f32x4 acc[2][2] = {};
  for (int kt = 0; kt < 16; ++kt) {
    const int k0 = kt * 32;
    if (wave < 2)
      async_copy16(Xb + (size_t)(n0 + ra) * DIM + k0 + ska, &As[wave * 512]);
    async_copy16(WbT + (size_t)srow * DIM + k0 + sk8, &Bs[wave * 512]);
    async_copy16(WbT + (size_t)(srow + 64) * DIM + k0 + sk8, &Bs[2048 + wave * 512]);
    __syncthreads();
    short8 a[2], b[2];
#pragma unroll
    for (int i = 0; i < 2; ++i) {
      const int R = i * 16 + fr;
      a[i] = *(const short8*)&As[R * 32 + swz_slot(R, g) * 8];
    }
#pragma unroll
    for (int jx = 0; jx < 2; ++jx) {
      const int R = wc * 32 + jx * 16 + fr;
      b[jx] = *(const short8*)&Bs[R * 32 + swz_slot(R, g) * 8];
    }
#pragma unroll
    for (int i = 0; i < 2; ++i)
#pragma unroll
      for (int jx = 0; jx < 2; ++jx)
        acc[i][jx] = __builtin_amdgcn_mfma_f32_16x16x32_bf16(a[i], b[jx], acc[i][jx], 0, 0, 0);
    __syncthreads();
  }

  const int rq = g * 4;
#pragma unroll
  for (int i = 0; i < 2; ++i)
#pragma unroll
    for (int jx = 0; jx < 2; ++jx)
#pragma unroll
      for (int q = 0; q < 4; ++q)
        lg[i * 16 + rq + q][wc * 32 + jx * 16 + fr] = acc[i][jx][q];
  __syncthreads();

  const int row = tid >> 3, c8 = tid & 7;
  const float4* lr = (const float4*)(&lg[row][c8 * 16]);
  float mx = -3.4e38f;
#pragma unroll
  for (int c = 0; c < 4; ++c) {
    float4 v = lr[c];
    mx = fmaxf(mx, fmaxf(fmaxf(v.x, v.y), fmaxf(v.z, v.w)));
  }
  mx = fmaxf(mx, __shfl_xor(mx, 1));
  mx = fmaxf(mx, __shfl_xor(mx, 2));
  mx = fmaxf(mx, __shfl_xor(mx, 4));
  float s = 0.f;
#pragma unroll
  for (int c = 0; c < 4; ++c) {
    float4 v = lr[c];
    s += __expf(v.x - mx) + __expf(v.y - mx) + __expf(v.z - mx) + __expf(v.w - mx);
  }
  s += __shfl_xor(s, 1);
  s += __shfl_xor(s, 2);
  s += __shfl_xor(s, 4);
  if (c8 == 0) phi_b[n0 + row] = mx + logf(s);
}

// =====================================================================
// Kernel 3: fused MX-fp8 GEMM + min epilogue — ALL-REGISTER with
// EXPLICIT double-buffered register sets. No LDS, no barriers.
// 256x256 tile, 8 waves (2wm x 4wn), wave = 128n x 64m.
// Both operands fragment-major [kt][8192][64B] in L2 (XCD-chunked).
// Schedule per tile t: MFMA(set t&1) -> reload set with S(t+2)
// (12 load-instrs) -> vmcnt(12) retires S(t+1). Tails vmcnt(0)/none.
// =====================================================================
__device__ __forceinline__ i32x8 ld2x16(const unsigned char* p0, const unsigned char* p1) {
  i32x4 lo = *(const i32x4*)p0;
  i32x4 hi = *(const i32x4*)p1;
  return __builtin_shufflevector(lo, hi, 0, 1, 2, 3, 4, 5, 6, 7);
}

__device__ __forceinline__ f32x16 mfma_mx(i32x8 a, i32x8 b, f32x16 c) {
  return __builtin_amdgcn_mfma_scale_f32_32x32x64_f8f6f4(a, b, c, 0, 0,
                                                         0, 0x7F, 0, 0x7F);
}

__device__ __forceinline__ void load_set(const unsigned char* __restrict__ Ab,
                                         const unsigned char* __restrict__ Bb,
                                         size_t koff, i32x8 (&A)[4], i32x8 (&B)[2]) {
#pragma unroll
  for (int i = 0; i < 4; ++i) {
    const unsigned char* p = Ab + koff + i * 2048;
    A[i] = ld2x16(p, p + 16);
  }
#pragma unroll
  for (int jx = 0; jx < 2; ++jx) {
    const unsigned char* p = Bb + koff + jx * 2048;
    B[jx] = ld2x16(p, p + 16);
  }
}

__device__ __forceinline__ void mfma_set(const i32x8 (&A)[4], const i32x8 (&B)[2],
                                         f32x16 (&acc)[4][2]) {
  __builtin_amdgcn_s_setprio(1);
#pragma unroll
  for (int i = 0; i < 4; ++i) acc[i][0] = mfma_mx(A[i], B[0], acc[i][0]);
#pragma unroll
  for (int i = 0; i < 4; ++i) acc[i][1] = mfma_mx(A[i], B[1], acc[i][1]);
  __builtin_amdgcn_s_setprio(0);
}

#define VM12 asm volatile("s_waitcnt vmcnt(12)" ::: "memory")
#define VM0  asm volatile("s_waitcnt vmcnt(0)" ::: "memory")

__global__ __launch_bounds__(512, 2)
void gemm_min_kernel(const unsigned char* __restrict__ XfT, const unsigned char* __restrict__ TfT,
                     const float* __restrict__ phi_b, unsigned* __restrict__ keys) {
  const int tid = threadIdx.x;
  const int wave = tid >> 6, lane = tid & 63;
  const int wm = wave >> 2, wn = wave & 3;
  const int fr5 = lane & 31, h = lane >> 5;

  // 2D XCD chunking: 8 chunks of 8n x 16m 256-tiles (~3MB / XCD L2)
  const int bid = blockIdx.x;
  const int xcd = bid & 7, idx = bid >> 3;
  const int nt = (xcd >> 1) * 8 + (idx >> 4);
  const int mt = (xcd & 1) * 16 + (idx & 15);
  const int n0 = nt * 256, m0 = mt * 256;

  const unsigned char* Ab = XfT + ((size_t)(n0 + wm * 128 + fr5)) * 64 + h * 32;
  const unsigned char* Bb = TfT + ((size_t)(m0 + wn * 64 + fr5)) * 64 + h * 32;
  const size_t KT = (size_t)N_PTS * 64;

  i32x8 A0[4], B0[2], A1[4], B1[2];
  load_set(Ab, Bb, 0, A0, B0);           // S(0)
  load_set(Ab, Bb, KT, A1, B1);          // S(1)
  VM12;                                   // S(0) landed

  f32x16 acc[4][2] = {};
  mfma_set(A0, B0, acc); load_set(Ab, Bb, 2 * KT, A0, B0); VM12;  // t0
  mfma_set(A1, B1, acc); load_set(Ab, Bb, 3 * KT, A1, B1); VM12;  // t1
  mfma_set(A0, B0, acc); load_set(Ab, Bb, 4 * KT, A0, B0); VM12;  // t2
  mfma_set(A1, B1, acc); load_set(Ab, Bb, 5 * KT, A1, B1); VM12;  // t3
  mfma_set(A0, B0, acc); load_set(Ab, Bb, 6 * KT, A0, B0); VM12;  // t4
  mfma_set(A1, B1, acc); load_set(Ab, Bb, 7 * KT, A1, B1); VM12;  // t5
  mfma_set(A0, B0, acc); VM0;                                      // t6
  mfma_set(A1, B1, acc);                                           // t7

  // Epilogue: v = phi_b[n] - dot; min over the wave's 128 rows per column.
  // 32x32 C/D layout (m74/m101): col = lane&31, row = (q&3)+8*(q>>2)+4*h
  float mv0 = 3.4e38f, mv1 = 3.4e38f;
#pragma unroll
  for (int i = 0; i < 4; ++i) {
    float pb[16];
#pragma unroll
    for (int q = 0; q < 16; ++q)
      pb[q] = phi_b[n0 + wm * 128 + i * 32 + (q & 3) + 8 * (q >> 2) + 4 * h];
#pragma unroll
    for (int q = 0; q < 16; ++q) {
      mv0 = fminf(mv0, pb[q] - acc[i][0][q]);
      mv1 = fminf(mv1, pb[q] - acc[i][1][q]);
    }
  }
  mv0 = fminf(mv0, __shfl_xor(mv0, 32));
  mv1 = fminf(mv1, __shfl_xor(mv1, 32));
  if (h == 0) {
    atomicMin(&keys[m0 + wn * 64 + fr5], fenc(mv0));
    atomicMin(&keys[m0 + wn * 64 + 32 + fr5], fenc(mv1));
  }
}

// =====================================================================
// Kernel 4: partial reduce — 64 blocks x 256 threads (unchanged).
// =====================================================================
__global__ __launch_bounds__(256)
void partial_kernel(const float* __restrict__ xsq, const float* __restrict__ phi_b,
                    const float* __restrict__ tsq, const unsigned* __restrict__ keys,
                    double* __restrict__ partials) {
  const int b = blockIdx.x, t = threadIdx.x;
  double s;
  if (b < 32) {
    const int n = b * 256 + t;
    s = 0.5 * (double)xsq[n] - (double)phi_b[n];
  } else {
    const int m = (b - 32) * 256 + t;
    s = 0.5 * (double)tsq[m] + (double)fdec(keys[m]);
  }
  const int lane = t & 63, wv = t >> 6;
#pragma unroll
  for (int k = 1; k <= 32; k <<= 1) s += __shfl_xor(s, k);
  __shared__ double ps[4];
  if (lane == 0) ps[wv] = s;
  __syncthreads();
  if (t == 0) partials[b] = ps[0] + ps[1] + ps[2] + ps[3];
}

// =====================================================================
// Kernel 5: final: sum 64 partials (fixed order), write scalar.
// =====================================================================
__global__ __launch_bounds__(64)
void final_kernel(const double* __restrict__ partials, float* __restrict__ out) {
  if (threadIdx.x == 0) {
    double a = 0.0, c = 0.0;
#pragma unroll
    for (int i = 0; i < 32; ++i) a += partials[i];
#pragma unroll
    for (int i = 32; i < 64; ++i) c += partials[i];
    out[0] = (float)(a / N_PTS + c / M_PTS);
  }
}

// =====================================================================
extern "C" void kernel_launch(void* const* d_in, const int* in_sizes, int n_in,
                              void* d_out, int out_size, void* d_ws, size_t ws_size,
                              hipStream_t stream) {
  const float* x = (const float*)d_in[0];
  const float* tgt = (const float*)d_in[1];
  const float* W = (const float*)d_in[2];

  char* ws = (char*)d_ws;
  const size_t XB_BYTES = (size_t)N_PTS * DIM * 2;   // bf16 x (for phi_b)
  const size_t XF_BYTES = (size_t)N_PTS * DIM;       // fp8 x (fragment-major)
  const size_t TF_BYTES = (size_t)M_PTS * DIM;       // fp8 t (fragment-major)
  const size_t WT_BYTES = (size_t)KDIM * DIM * 2;
  unsigned short* Xb = (unsigned short*)ws;
  unsigned char* XfT = (unsigned char*)(ws + XB_BYTES);
  unsigned char* TfT = (unsigned char*)(ws + XB_BYTES + XF_BYTES);
  unsigned short* WbT = (unsigned short*)(ws + XB_BYTES + XF_BYTES + TF_BYTES);
  float* phi_b = (float*)(ws + XB_BYTES + XF_BYTES + TF_BYTES + WT_BYTES);
  float* xsq = phi_b + N_PTS;
  float* tsq = xsq + N_PTS;
  unsigned* keys = (unsigned*)(tsq + M_PTS);
  double* partials = (double*)(keys + M_PTS + 64);   // 8B-aligned region

  const int prep_blocks = (N_PTS + M_PTS) / 4 + (KDIM * DIM) / 256;
  prep_all_kernel<<<prep_blocks, 256, 0, stream>>>(x, tgt, W, Xb, XfT, TfT, WbT,
                                                   xsq, tsq, keys);
  phi_b_kernel<<<N_PTS / 32, 256, 0, stream>>>((const short*)Xb, (const short*)WbT, phi_b);
  gemm_min_kernel<<<(N_PTS / 256) * (M_PTS / 256), 512, 0, stream>>>(XfT, TfT, phi_b, keys);
  partial_kernel<<<64, 256, 0, stream>>>(xsq, phi_b, tsq, keys, partials);
  final_kernel<<<1, 64, 0, stream>>>(partials, (float*)d_out);
}

// Round 19
// 67.705 us; speedup vs baseline: 1.1704x; 1.1704x over previous
//
#include <hip/hip_runtime.h>
#include <hip/hip_bf16.h>
#include <stdint.h>

typedef __attribute__((ext_vector_type(8))) short short8;
typedef __attribute__((ext_vector_type(4))) float f32x4;
typedef __attribute__((ext_vector_type(16))) float f32x16;
typedef __attribute__((ext_vector_type(4))) int i32x4;
typedef __attribute__((ext_vector_type(8))) int i32x8;

#define N_PTS 8192
#define M_PTS 8192
#define DIM   512
#define KDIM  128

// ---- float <-> order-preserving uint key (for atomicMin on float) ----
__device__ __forceinline__ unsigned fenc(float f) {
  unsigned u = __float_as_uint(f);
  return (u & 0x80000000u) ? ~u : (u | 0x80000000u);
}
__device__ __forceinline__ float fdec(unsigned k) {
  unsigned u = (k & 0x80000000u) ? (k ^ 0x80000000u) : ~k;
  return __uint_as_float(u);
}

__device__ __forceinline__ unsigned short f2bf(float f) {
  union { __hip_bfloat16 h; unsigned short u; } c;
  c.h = __float2bfloat16(f);
  return c.u;
}

// ---- float -> OCP e4m3fn, RNE, flush |f|<2^-6 to 0 (x,t ~ N(0,1)) ----
__device__ __forceinline__ unsigned f2e4m3(float f) {
  unsigned u = __float_as_uint(f);
  unsigned s = (u >> 24) & 0x80;
  unsigned mag = u & 0x7fffffffu;
  unsigned r = mag + 0x0007ffffu + ((mag >> 20) & 1u);  // RNE to 3 mantissa bits
  int e = (int)(r >> 23) - 127;
  if (e < -6) return s;                                 // flush tiny to zero
  unsigned m = (r >> 20) & 7u;
  return s | (unsigned)((e + 7) << 3) | m;
}

// ---- async global -> LDS, 16B per lane ----
__device__ __forceinline__ void async_copy16(const void* g, void* l) {
  __builtin_amdgcn_global_load_lds(
      (const __attribute__((address_space(1))) void*)g,
      (__attribute__((address_space(3))) void*)l, 16, 0, 0);
}

// ---- bf16 LDS slot swizzle (proven 0-conflict geometry) ----
__device__ __forceinline__ int swz_slot(int row, int slot) {
  return slot ^ ((row >> 1) & 3);
}

// ---- A-tile chunk key (row bits 1..4; stage/read-consistent) ----
__device__ __forceinline__ int chunk_key(int row) {
  return ((row >> 1) & 3) ^ ((row >> 3) & 1) ^ (((row >> 4) & 1) << 1);
}

#define BARRIER __builtin_amdgcn_s_barrier()

// =====================================================================
// Kernel 1: prep-all (r16/r17 form). Blocks < 4096: one wave per row:
// x -> Xb(bf16) + Xf8(e4m3 plain rows) + xsq; target -> TfT (e4m3,
// fragment-major [kt][8192][64B]) + tsq + key init.
// Blocks >= 4096: W [D][K] fp32 -> WbT [K][D] bf16 transpose-cast.
// =====================================================================
__global__ __launch_bounds__(256)
void prep_all_kernel(const float* __restrict__ x, const float* __restrict__ tgt,
                     const float* __restrict__ W,
                     unsigned short* __restrict__ Xb, unsigned char* __restrict__ Xf8,
                     unsigned char* __restrict__ TfT, unsigned short* __restrict__ WbT,
                     float* __restrict__ xsq, float* __restrict__ tsq,
                     unsigned* __restrict__ keys) {
  const int bid = blockIdx.x;
  const int tid = threadIdx.x;
  if (bid >= (N_PTS + M_PTS) / 4) {
    const int o = (bid - (N_PTS + M_PTS) / 4) * 256 + tid;  // 0..65535
    const int k = o >> 9, d = o & 511;
    WbT[o] = f2bf(W[d * KDIM + k]);
    return;
  }
  const int gw = (bid * 256 + tid) >> 6;
  const int j = tid & 63;
  float s;
  if (gw < N_PTS) {
    const float* src = x + (size_t)gw * DIM + j * 8;
    float4 v0 = *(const float4*)src;
    float4 v1 = *(const float4*)(src + 4);
    s = v0.x * v0.x + v0.y * v0.y + v0.z * v0.z + v0.w * v0.w +
        v1.x * v1.x + v1.y * v1.y + v1.z * v1.z + v1.w * v1.w;
    unsigned short* db = Xb + (size_t)gw * DIM + j * 8;
    ushort4 ob0, ob1;
    ob0.x = f2bf(v0.x); ob0.y = f2bf(v0.y); ob0.z = f2bf(v0.z); ob0.w = f2bf(v0.w);
    ob1.x = f2bf(v1.x); ob1.y = f2bf(v1.y); ob1.z = f2bf(v1.z); ob1.w = f2bf(v1.w);
    *(ushort4*)db = ob0;
    *(ushort4*)(db + 4) = ob1;
    unsigned long long p = (unsigned long long)f2e4m3(v0.x)
        | ((unsigned long long)f2e4m3(v0.y) << 8)
        | ((unsigned long long)f2e4m3(v0.z) << 16)
        | ((unsigned long long)f2e4m3(v0.w) << 24)
        | ((unsigned long long)f2e4m3(v1.x) << 32)
        | ((unsigned long long)f2e4m3(v1.y) << 40)
        | ((unsigned long long)f2e4m3(v1.z) << 48)
        | ((unsigned long long)f2e4m3(v1.w) << 56);
    *(unsigned long long*)(Xf8 + (size_t)gw * DIM + j * 8) = p;
#pragma unroll
    for (int m = 1; m <= 32; m <<= 1) s += __shfl_xor(s, m);
    if (j == 0) xsq[gw] = s;
  } else {
    const int tr = gw - N_PTS;
    const float* src = tgt + (size_t)tr * DIM + j * 8;
    float4 v0 = *(const float4*)src;
    float4 v1 = *(const float4*)(src + 4);
    s = v0.x * v0.x + v0.y * v0.y + v0.z * v0.z + v0.w * v0.w +
        v1.x * v1.x + v1.y * v1.y + v1.z * v1.z + v1.w * v1.w;
    unsigned long long p = (unsigned long long)f2e4m3(v0.x)
        | ((unsigned long long)f2e4m3(v0.y) << 8)
        | ((unsigned long long)f2e4m3(v0.z) << 16)
        | ((unsigned long long)f2e4m3(v0.w) << 24)
        | ((unsigned long long)f2e4m3(v1.x) << 32)
        | ((unsigned long long)f2e4m3(v1.y) << 40)
        | ((unsigned long long)f2e4m3(v1.z) << 48)
        | ((unsigned long long)f2e4m3(v1.w) << 56);
    // fragment-major: [kt = j>>3][row tr][byte (j&7)*8]
    *(unsigned long long*)(TfT + ((size_t)(j >> 3) * M_PTS + tr) * 64 + (j & 7) * 8) = p;
#pragma unroll
    for (int m = 1; m <= 32; m <<= 1) s += __shfl_xor(s, m);
    if (j == 0) { tsq[tr] = s; keys[tr] = 0xFFFFFFFFu; }
  }
}

// =====================================================================
// Kernel 2: phi_b — 256 blocks x 32 rows (r16 retile, unchanged).
// =====================================================================
__global__ __launch_bounds__(256)
void phi_b_kernel(const short* __restrict__ Xb, const short* __restrict__ WbT,
                  float* __restrict__ phi_b) {
  __shared__ __align__(16) short As[32 * 32];
  __shared__ __align__(16) short Bs[128 * 32];
  __shared__ __align__(16) float lg[32][136];

  const int tid = threadIdx.x;
  const int wave = tid >> 6, lane = tid & 63;
  const int n0 = blockIdx.x * 32;
  const int fr = lane & 15, g = lane >> 4;
  const int wc = wave;

  const int srow = tid >> 2;
  const int sk8 = swz_slot(srow, tid & 3) * 8;
  const int ra = tid >> 2;
  const int ska = swz_slot(ra, tid & 3) * 8;

  f32x4 acc[2][2] = {};
  for (int kt = 0; kt < 16; ++kt) {
    const int k0 = kt * 32;
    if (wave < 2)
      async_copy16(Xb + (size_t)(n0 + ra) * DIM + k0 + ska, &As[wave * 512]);
    async_copy16(WbT + (size_t)srow * DIM + k0 + sk8, &Bs[wave * 512]);
    async_copy16(WbT + (size_t)(srow + 64) * DIM + k0 + sk8, &Bs[2048 + wave * 512]);
    __syncthreads();
    short8 a[2], b[2];
#pragma unroll
    for (int i = 0; i < 2; ++i) {
      const int R = i * 16 + fr;
      a[i] = *(const short8*)&As[R * 32 + swz_slot(R, g) * 8];
    }
#pragma unroll
    for (int jx = 0; jx < 2; ++jx) {
      const int R = wc * 32 + jx * 16 + fr;
      b[jx] = *(const short8*)&Bs[R * 32 + swz_slot(R, g) * 8];
    }
#pragma unroll
    for (int i = 0; i < 2; ++i)
#pragma unroll
      for (int jx = 0; jx < 2; ++jx)
        acc[i][jx] = __builtin_amdgcn_mfma_f32_16x16x32_bf16(a[i], b[jx], acc[i][jx], 0, 0, 0);
    __syncthreads();
  }

  const int rq = g * 4;
#pragma unroll
  for (int i = 0; i < 2; ++i)
#pragma unroll
    for (int jx = 0; jx < 2; ++jx)
#pragma unroll
      for (int q = 0; q < 4; ++q)
        lg[i * 16 + rq + q][wc * 32 + jx * 16 + fr] = acc[i][jx][q];
  __syncthreads();

  const int row = tid >> 3, c8 = tid & 7;
  const float4* lr = (const float4*)(&lg[row][c8 * 16]);
  float mx = -3.4e38f;
#pragma unroll
  for (int c = 0; c < 4; ++c) {
    float4 v = lr[c];
    mx = fmaxf(mx, fmaxf(fmaxf(v.x, v.y), fmaxf(v.z, v.w)));
  }
  mx = fmaxf(mx, __shfl_xor(mx, 1));
  mx = fmaxf(mx, __shfl_xor(mx, 2));
  mx = fmaxf(mx, __shfl_xor(mx, 4));
  float s = 0.f;
#pragma unroll
  for (int c = 0; c < 4; ++c) {
    float4 v = lr[c];
    s += __expf(v.x - mx) + __expf(v.y - mx) + __expf(v.z - mx) + __expf(v.w - mx);
  }
  s += __shfl_xor(s, 1);
  s += __shfl_xor(s, 2);
  s += __shfl_xor(s, 4);
  if (c8 == 0) phi_b[n0 + row] = mx + logf(s);
}

// =====================================================================
// Kernel 3: fused MX-fp8 GEMM + min epilogue — BARRIER-FREE K-LOOP.
// 256x256 tile, 8 waves (2Mx4N). ALL 8 K-tiles of A pre-staged into
// 128KB LDS in the prologue (ONE vmcnt(0)+barrier); after that, waves
// run fully independently: per tile 8 ds_read_b128 (proven r12 swizzle)
// + 2-deep named-set B prefetch from fragment-major TfT (L2, r17) +
// 8 MFMA. All waits compiler-counted (exact register deps).
// =====================================================================
__device__ __forceinline__ void stgA(const unsigned char* __restrict__ mat,
                                     int rowbase, int kbyte,
                                     unsigned char* dst, int tid) {
  const int r = tid >> 2, d = tid & 3;
  async_copy16(mat + (size_t)(rowbase + r) * DIM + kbyte + ((d ^ chunk_key(r)) << 4),
               dst + (tid >> 6) * 1024);
}

__device__ __forceinline__ i32x8 ld2x16(const unsigned char* p0, const unsigned char* p1) {
  i32x4 lo = *(const i32x4*)p0;
  i32x4 hi = *(const i32x4*)p1;
  return __builtin_shufflevector(lo, hi, 0, 1, 2, 3, 4, 5, 6, 7);
}

__device__ __forceinline__ f32x16 mfma_mx(i32x8 a, i32x8 b, f32x16 c) {
  return __builtin_amdgcn_mfma_scale_f32_32x32x64_f8f6f4(a, b, c, 0, 0,
                                                         0, 0x7F, 0, 0x7F);
}

// one K64 tile: read A frags from this tile's LDS buffer; optionally
// load B(t+2) into fbn; 8 MFMA on (fa, fb).
template <bool LDB>
__device__ __forceinline__ void tile_nf(const unsigned char* __restrict__ Abuf,
                                        const unsigned char* __restrict__ Bnx,
                                        int aoff, i32x8 (&fb)[2], i32x8 (&fbn)[2],
                                        f32x16 (&acc)[4][2]) {
  i32x8 fa[4];
#pragma unroll
  for (int i = 0; i < 4; ++i)
    fa[i] = ld2x16(Abuf + aoff + i * 2048, Abuf + ((aoff + i * 2048) ^ 16));
  if (LDB) {
    fbn[0] = ld2x16(Bnx, Bnx + 16);
    fbn[1] = ld2x16(Bnx + 2048, Bnx + 2048 + 16);
  }
  __builtin_amdgcn_s_setprio(1);
#pragma unroll
  for (int i = 0; i < 4; ++i) acc[i][0] = mfma_mx(fa[i], fb[0], acc[i][0]);
#pragma unroll
  for (int i = 0; i < 4; ++i) acc[i][1] = mfma_mx(fa[i], fb[1], acc[i][1]);
  __builtin_amdgcn_s_setprio(0);
}

__global__ __launch_bounds__(512, 1)
void gemm_min_kernel(const unsigned char* __restrict__ Xf, const unsigned char* __restrict__ TfT,
                     const float* __restrict__ phi_b, unsigned* __restrict__ keys) {
  __shared__ __align__(16) unsigned char lds8[131072];   // 8 x 16KB A tiles

  const int tid = threadIdx.x;
  const int wave = tid >> 6, lane = tid & 63;
  const int wm = wave >> 2, wn = wave & 3;
  const int fr5 = lane & 31, h = lane >> 5;

  // 2D XCD chunking: 8 chunks of 8n x 16m tiles (~3MB working set / XCD L2)
  const int bid = blockIdx.x;
  const int xcd = bid & 7, idx = bid >> 3;
  const int nt = (xcd >> 1) * 8 + (idx >> 4);
  const int mt = (xcd & 1) * 16 + (idx & 15);
  const int n0 = nt * 256, m0 = mt * 256;

  const int aoff = (wm * 128 + fr5) * 64 + (((h << 1) ^ chunk_key(fr5)) << 4);

  const unsigned char* Bb = TfT + ((size_t)(m0 + wn * 64 + fr5)) * 64 + h * 32;
#define BK_T(kt) (Bb + (size_t)(kt) * (M_PTS * 64))

  // prologue: stage ALL 8 A K-tiles (16 instrs/thread); one drain+barrier.
#pragma unroll
  for (int kt = 0; kt < 8; ++kt) {
    stgA(Xf, n0, kt * 64, lds8 + kt * 16384, tid);
    stgA(Xf, n0 + 128, kt * 64, lds8 + kt * 16384 + 8192, tid);
  }
  asm volatile("s_waitcnt vmcnt(0)" ::: "memory");
  BARRIER;

  // B register pipeline: 3 named sets, 2-deep prefetch (r17).
  i32x8 s0[2], s1[2], s2[2];
  s0[0] = ld2x16(BK_T(0), BK_T(0) + 16);
  s0[1] = ld2x16(BK_T(0) + 2048, BK_T(0) + 2048 + 16);
  s1[0] = ld2x16(BK_T(1), BK_T(1) + 16);
  s1[1] = ld2x16(BK_T(1) + 2048, BK_T(1) + 2048 + 16);

  f32x16 acc[4][2] = {};
  tile_nf<true>(lds8 + 0 * 16384, BK_T(2), aoff, s0, s2, acc);   // t0
  tile_nf<true>(lds8 + 1 * 16384, BK_T(3), aoff, s1, s0, acc);   // t1
  tile_nf<true>(lds8 + 2 * 16384, BK_T(4), aoff, s2, s1, acc);   // t2
  tile_nf<true>(lds8 + 3 * 16384, BK_T(5), aoff, s0, s2, acc);   // t3
  tile_nf<true>(lds8 + 4 * 16384, BK_T(6), aoff, s1, s0, acc);   // t4
  tile_nf<true>(lds8 + 5 * 16384, BK_T(7), aoff, s2, s1, acc);   // t5
  tile_nf<false>(lds8 + 6 * 16384, BK_T(7), aoff, s0, s2, acc);  // t6
  tile_nf<false>(lds8 + 7 * 16384, BK_T(7), aoff, s1, s2, acc);  // t7

  // Epilogue: v = phi_b[n] - dot; min over the wave's 128 rows per column.
  // 32x32 C/D layout (m74/m101): col = lane&31, row = (q&3)+8*(q>>2)+4*h
  float mv0 = 3.4e38f, mv1 = 3.4e38f;
#pragma unroll
  for (int i = 0; i < 4; ++i) {
    float pb[16];
#pragma unroll
    for (int q = 0; q < 16; ++q)
      pb[q] = phi_b[n0 + wm * 128 + i * 32 + (q & 3) + 8 * (q >> 2) + 4 * h];
#pragma unroll
    for (int q = 0; q < 16; ++q) {
      mv0 = fminf(mv0, pb[q] - acc[i][0][q]);
      mv1 = fminf(mv1, pb[q] - acc[i][1][q]);
    }
  }
  mv0 = fminf(mv0, __shfl_xor(mv0, 32));
  mv1 = fminf(mv1, __shfl_xor(mv1, 32));
  if (h == 0) {
    atomicMin(&keys[m0 + wn * 64 + fr5], fenc(mv0));
    atomicMin(&keys[m0 + wn * 64 + 32 + fr5], fenc(mv1));
  }
#undef BK_T
}

// =====================================================================
// Kernel 4: partial reduce — 64 blocks x 256 threads (unchanged).
// =====================================================================
__global__ __launch_bounds__(256)
void partial_kernel(const float* __restrict__ xsq, const float* __restrict__ phi_b,
                    const float* __restrict__ tsq, const unsigned* __restrict__ keys,
                    double* __restrict__ partials) {
  const int b = blockIdx.x, t = threadIdx.x;
  double s;
  if (b < 32) {
    const int n = b * 256 + t;
    s = 0.5 * (double)xsq[n] - (double)phi_b[n];
  } else {
    const int m = (b - 32) * 256 + t;
    s = 0.5 * (double)tsq[m] + (double)fdec(keys[m]);
  }
  const int lane = t & 63, wv = t >> 6;
#pragma unroll
  for (int k = 1; k <= 32; k <<= 1) s += __shfl_xor(s, k);
  __shared__ double ps[4];
  if (lane == 0) ps[wv] = s;
  __syncthreads();
  if (t == 0) partials[b] = ps[0] + ps[1] + ps[2] + ps[3];
}

// =====================================================================
// Kernel 5: final: sum 64 partials (fixed order), write scalar.
// =====================================================================
__global__ __launch_bounds__(64)
void final_kernel(const double* __restrict__ partials, float* __restrict__ out) {
  if (threadIdx.x == 0) {
    double a = 0.0, c = 0.0;
#pragma unroll
    for (int i = 0; i < 32; ++i) a += partials[i];
#pragma unroll
    for (int i = 32; i < 64; ++i) c += partials[i];
    out[0] = (float)(a / N_PTS + c / M_PTS);
  }
}

// =====================================================================
extern "C" void kernel_launch(void* const* d_in, const int* in_sizes, int n_in,
                              void* d_out, int out_size, void* d_ws, size_t ws_size,
                              hipStream_t stream) {
  const float* x = (const float*)d_in[0];
  const float* tgt = (const float*)d_in[1];
  const float* W = (const float*)d_in[2];

  char* ws = (char*)d_ws;
  const size_t XB_BYTES = (size_t)N_PTS * DIM * 2;   // bf16 x (for phi_b)
  const size_t XF_BYTES = (size_t)N_PTS * DIM;       // fp8 x (plain row order)
  const size_t TF_BYTES = (size_t)M_PTS * DIM;       // fp8 t (fragment-major)
  const size_t WT_BYTES = (size_t)KDIM * DIM * 2;
  unsigned short* Xb = (unsigned short*)ws;
  unsigned char* Xf8 = (unsigned char*)(ws + XB_BYTES);
  unsigned char* TfT = (unsigned char*)(ws + XB_BYTES + XF_BYTES);
  unsigned short* WbT = (unsigned short*)(ws + XB_BYTES + XF_BYTES + TF_BYTES);
  float* phi_b = (float*)(ws + XB_BYTES + XF_BYTES + TF_BYTES + WT_BYTES);
  float* xsq = phi_b + N_PTS;
  float* tsq = xsq + N_PTS;
  unsigned* keys = (unsigned*)(tsq + M_PTS);
  double* partials = (double*)(keys + M_PTS + 64);   // 8B-aligned region

  const int prep_blocks = (N_PTS + M_PTS) / 4 + (KDIM * DIM) / 256;
  prep_all_kernel<<<prep_blocks, 256, 0, stream>>>(x, tgt, W, Xb, Xf8, TfT, WbT,
                                                   xsq, tsq, keys);
  phi_b_kernel<<<N_PTS / 32, 256, 0, stream>>>((const short*)Xb, (const short*)WbT, phi_b);
  gemm_min_kernel<<<(N_PTS / 256) * (M_PTS / 256), 512, 0, stream>>>(Xf8, TfT, phi_b, keys);
  partial_kernel<<<64, 256, 0, stream>>>(xsq, phi_b, tsq, keys, partials);
  final_kernel<<<1, 64, 0, stream>>>(partials, (float*)d_out);
}

// Round 20
// 67.588 us; speedup vs baseline: 1.1725x; 1.0017x over previous
//
#include <hip/hip_runtime.h>
#include <hip/hip_bf16.h>
#include <stdint.h>

typedef __attribute__((ext_vector_type(8))) short short8;
typedef __attribute__((ext_vector_type(4))) float f32x4;
typedef __attribute__((ext_vector_type(16))) float f32x16;
typedef __attribute__((ext_vector_type(4))) int i32x4;
typedef __attribute__((ext_vector_type(8))) int i32x8;

#define N_PTS 8192
#define M_PTS 8192
#define DIM   512
#define KDIM  128

// ---- float <-> order-preserving uint key (for atomicMin on float) ----
__device__ __forceinline__ unsigned fenc(float f) {
  unsigned u = __float_as_uint(f);
  return (u & 0x80000000u) ? ~u : (u | 0x80000000u);
}
__device__ __forceinline__ float fdec(unsigned k) {
  unsigned u = (k & 0x80000000u) ? (k ^ 0x80000000u) : ~k;
  return __uint_as_float(u);
}

__device__ __forceinline__ unsigned short f2bf(float f) {
  union { __hip_bfloat16 h; unsigned short u; } c;
  c.h = __float2bfloat16(f);
  return c.u;
}

// ---- float -> OCP e4m3fn, RNE, flush |f|<2^-6 to 0 (x,t ~ N(0,1)) ----
__device__ __forceinline__ unsigned f2e4m3(float f) {
  unsigned u = __float_as_uint(f);
  unsigned s = (u >> 24) & 0x80;
  unsigned mag = u & 0x7fffffffu;
  unsigned r = mag + 0x0007ffffu + ((mag >> 20) & 1u);  // RNE to 3 mantissa bits
  int e = (int)(r >> 23) - 127;
  if (e < -6) return s;                                 // flush tiny to zero
  unsigned m = (r >> 20) & 7u;
  return s | (unsigned)((e + 7) << 3) | m;
}

// ---- async global -> LDS, 16B per lane ----
__device__ __forceinline__ void async_copy16(const void* g, void* l) {
  __builtin_amdgcn_global_load_lds(
      (const __attribute__((address_space(1))) void*)g,
      (__attribute__((address_space(3))) void*)l, 16, 0, 0);
}

// ---- bf16 LDS slot swizzle (proven 0-conflict geometry) ----
__device__ __forceinline__ int swz_slot(int row, int slot) {
  return slot ^ ((row >> 1) & 3);
}

// ---- A-tile chunk key (row bits 1..4; stage/read-consistent) ----
__device__ __forceinline__ int chunk_key(int row) {
  return ((row >> 1) & 3) ^ ((row >> 3) & 1) ^ (((row >> 4) & 1) << 1);
}

#define BARRIER __builtin_amdgcn_s_barrier()

// =====================================================================
// Kernel 1: prep-all (unchanged). Blocks < 4096: one wave per row:
// x -> Xb(bf16) + Xf8(e4m3 plain rows) + xsq; target -> TfT (e4m3,
// fragment-major [kt][8192][64B]) + tsq + key init.
// Blocks >= 4096: W [D][K] fp32 -> WbT [K][D] bf16 transpose-cast.
// =====================================================================
__global__ __launch_bounds__(256)
void prep_all_kernel(const float* __restrict__ x, const float* __restrict__ tgt,
                     const float* __restrict__ W,
                     unsigned short* __restrict__ Xb, unsigned char* __restrict__ Xf8,
                     unsigned char* __restrict__ TfT, unsigned short* __restrict__ WbT,
                     float* __restrict__ xsq, float* __restrict__ tsq,
                     unsigned* __restrict__ keys) {
  const int bid = blockIdx.x;
  const int tid = threadIdx.x;
  if (bid >= (N_PTS + M_PTS) / 4) {
    const int o = (bid - (N_PTS + M_PTS) / 4) * 256 + tid;  // 0..65535
    const int k = o >> 9, d = o & 511;
    WbT[o] = f2bf(W[d * KDIM + k]);
    return;
  }
  const int gw = (bid * 256 + tid) >> 6;
  const int j = tid & 63;
  float s;
  if (gw < N_PTS) {
    const float* src = x + (size_t)gw * DIM + j * 8;
    float4 v0 = *(const float4*)src;
    float4 v1 = *(const float4*)(src + 4);
    s = v0.x * v0.x + v0.y * v0.y + v0.z * v0.z + v0.w * v0.w +
        v1.x * v1.x + v1.y * v1.y + v1.z * v1.z + v1.w * v1.w;
    unsigned short* db = Xb + (size_t)gw * DIM + j * 8;
    ushort4 ob0, ob1;
    ob0.x = f2bf(v0.x); ob0.y = f2bf(v0.y); ob0.z = f2bf(v0.z); ob0.w = f2bf(v0.w);
    ob1.x = f2bf(v1.x); ob1.y = f2bf(v1.y); ob1.z = f2bf(v1.z); ob1.w = f2bf(v1.w);
    *(ushort4*)db = ob0;
    *(ushort4*)(db + 4) = ob1;
    unsigned long long p = (unsigned long long)f2e4m3(v0.x)
        | ((unsigned long long)f2e4m3(v0.y) << 8)
        | ((unsigned long long)f2e4m3(v0.z) << 16)
        | ((unsigned long long)f2e4m3(v0.w) << 24)
        | ((unsigned long long)f2e4m3(v1.x) << 32)
        | ((unsigned long long)f2e4m3(v1.y) << 40)
        | ((unsigned long long)f2e4m3(v1.z) << 48)
        | ((unsigned long long)f2e4m3(v1.w) << 56);
    *(unsigned long long*)(Xf8 + (size_t)gw * DIM + j * 8) = p;
#pragma unroll
    for (int m = 1; m <= 32; m <<= 1) s += __shfl_xor(s, m);
    if (j == 0) xsq[gw] = s;
  } else {
    const int tr = gw - N_PTS;
    const float* src = tgt + (size_t)tr * DIM + j * 8;
    float4 v0 = *(const float4*)src;
    float4 v1 = *(const float4*)(src + 4);
    s = v0.x * v0.x + v0.y * v0.y + v0.z * v0.z + v0.w * v0.w +
        v1.x * v1.x + v1.y * v1.y + v1.z * v1.z + v1.w * v1.w;
    unsigned long long p = (unsigned long long)f2e4m3(v0.x)
        | ((unsigned long long)f2e4m3(v0.y) << 8)
        | ((unsigned long long)f2e4m3(v0.z) << 16)
        | ((unsigned long long)f2e4m3(v0.w) << 24)
        | ((unsigned long long)f2e4m3(v1.x) << 32)
        | ((unsigned long long)f2e4m3(v1.y) << 40)
        | ((unsigned long long)f2e4m3(v1.z) << 48)
        | ((unsigned long long)f2e4m3(v1.w) << 56);
    // fragment-major: [kt = j>>3][row tr][byte (j&7)*8]
    *(unsigned long long*)(TfT + ((size_t)(j >> 3) * M_PTS + tr) * 64 + (j & 7) * 8) = p;
#pragma unroll
    for (int m = 1; m <= 32; m <<= 1) s += __shfl_xor(s, m);
    if (j == 0) { tsq[tr] = s; keys[tr] = 0xFFFFFFFFu; }
  }
}

// =====================================================================
// Kernel 2: phi_b — 256 blocks x 32 rows (r16 retile, unchanged).
// =====================================================================
__global__ __launch_bounds__(256)
void phi_b_kernel(const short* __restrict__ Xb, const short* __restrict__ WbT,
                  float* __restrict__ phi_b) {
  __shared__ __align__(16) short As[32 * 32];
  __shared__ __align__(16) short Bs[128 * 32];
  __shared__ __align__(16) float lg[32][136];

  const int tid = threadIdx.x;
  const int wave = tid >> 6, lane = tid & 63;
  const int n0 = blockIdx.x * 32;
  const int fr = lane & 15, g = lane >> 4;
  const int wc = wave;

  const int srow = tid >> 2;
  const int sk8 = swz_slot(srow, tid & 3) * 8;
  const int ra = tid >> 2;
  const int ska = swz_slot(ra, tid & 3) * 8;

  f32x4 acc[2][2] = {};
  for (int kt = 0; kt < 16; ++kt) {
    const int k0 = kt * 32;
    if (wave < 2)
      async_copy16(Xb + (size_t)(n0 + ra) * DIM + k0 + ska, &As[wave * 512]);
    async_copy16(WbT + (size_t)srow * DIM + k0 + sk8, &Bs[wave * 512]);
    async_copy16(WbT + (size_t)(srow + 64) * DIM + k0 + sk8, &Bs[2048 + wave * 512]);
    __syncthreads();
    short8 a[2], b[2];
#pragma unroll
    for (int i = 0; i < 2; ++i) {
      const int R = i * 16 + fr;
      a[i] = *(const short8*)&As[R * 32 + swz_slot(R, g) * 8];
    }
#pragma unroll
    for (int jx = 0; jx < 2; ++jx) {
      const int R = wc * 32 + jx * 16 + fr;
      b[jx] = *(const short8*)&Bs[R * 32 + swz_slot(R, g) * 8];
    }
#pragma unroll
    for (int i = 0; i < 2; ++i)
#pragma unroll
      for (int jx = 0; jx < 2; ++jx)
        acc[i][jx] = __builtin_amdgcn_mfma_f32_16x16x32_bf16(a[i], b[jx], acc[i][jx], 0, 0, 0);
    __syncthreads();
  }

  const int rq = g * 4;
#pragma unroll
  for (int i = 0; i < 2; ++i)
#pragma unroll
    for (int jx = 0; jx < 2; ++jx)
#pragma unroll
      for (int q = 0; q < 4; ++q)
        lg[i * 16 + rq + q][wc * 32 + jx * 16 + fr] = acc[i][jx][q];
  __syncthreads();

  const int row = tid >> 3, c8 = tid & 7;
  const float4* lr = (const float4*)(&lg[row][c8 * 16]);
  float mx = -3.4e38f;
#pragma unroll
  for (int c = 0; c < 4; ++c) {
    float4 v = lr[c];
    mx = fmaxf(mx, fmaxf(fmaxf(v.x, v.y), fmaxf(v.z, v.w)));
  }
  mx = fmaxf(mx, __shfl_xor(mx, 1));
  mx = fmaxf(mx, __shfl_xor(mx, 2));
  mx = fmaxf(mx, __shfl_xor(mx, 4));
  float s = 0.f;
#pragma unroll
  for (int c = 0; c < 4; ++c) {
    float4 v = lr[c];
    s += __expf(v.x - mx) + __expf(v.y - mx) + __expf(v.z - mx) + __expf(v.w - mx);
  }
  s += __shfl_xor(s, 1);
  s += __shfl_xor(s, 2);
  s += __shfl_xor(s, 4);
  if (c8 == 0) phi_b[n0 + row] = mx + logf(s);
}

// =====================================================================
// Kernel 3: fused MX-fp8 GEMM + min epilogue — barrier-free K-loop
// (r19) with SPLIT prologue drain: vmcnt(16) covers tiles 0-3 only
// (tiles 4-7 staging overlaps compute of t0-t3); vmcnt(24) after t3
// retires all 16 stage instrs (VMEM FIFO retirement). 2 barriers.
// =====================================================================
__device__ __forceinline__ void stgA(const unsigned char* __restrict__ mat,
                                     int rowbase, int kbyte,
                                     unsigned char* dst, int tid) {
  const int r = tid >> 2, d = tid & 3;
  async_copy16(mat + (size_t)(rowbase + r) * DIM + kbyte + ((d ^ chunk_key(r)) << 4),
               dst + (tid >> 6) * 1024);
}

__device__ __forceinline__ i32x8 ld2x16(const unsigned char* p0, const unsigned char* p1) {
  i32x4 lo = *(const i32x4*)p0;
  i32x4 hi = *(const i32x4*)p1;
  return __builtin_shufflevector(lo, hi, 0, 1, 2, 3, 4, 5, 6, 7);
}

__device__ __forceinline__ f32x16 mfma_mx(i32x8 a, i32x8 b, f32x16 c) {
  return __builtin_amdgcn_mfma_scale_f32_32x32x64_f8f6f4(a, b, c, 0, 0,
                                                         0, 0x7F, 0, 0x7F);
}

template <bool LDB>
__device__ __forceinline__ void tile_nf(const unsigned char* __restrict__ Abuf,
                                        const unsigned char* __restrict__ Bnx,
                                        int aoff, i32x8 (&fb)[2], i32x8 (&fbn)[2],
                                        f32x16 (&acc)[4][2]) {
  i32x8 fa[4];
#pragma unroll
  for (int i = 0; i < 4; ++i)
    fa[i] = ld2x16(Abuf + aoff + i * 2048, Abuf + ((aoff + i * 2048) ^ 16));
  if (LDB) {
    fbn[0] = ld2x16(Bnx, Bnx + 16);
    fbn[1] = ld2x16(Bnx + 2048, Bnx + 2048 + 16);
  }
  __builtin_amdgcn_s_setprio(1);
#pragma unroll
  for (int i = 0; i < 4; ++i) acc[i][0] = mfma_mx(fa[i], fb[0], acc[i][0]);
#pragma unroll
  for (int i = 0; i < 4; ++i) acc[i][1] = mfma_mx(fa[i], fb[1], acc[i][1]);
  __builtin_amdgcn_s_setprio(0);
}

__global__ __launch_bounds__(512, 1)
void gemm_min_kernel(const unsigned char* __restrict__ Xf, const unsigned char* __restrict__ TfT,
                     const float* __restrict__ phi_b, unsigned* __restrict__ keys) {
  __shared__ __align__(16) unsigned char lds8[131072];   // 8 x 16KB A tiles

  const int tid = threadIdx.x;
  const int wave = tid >> 6, lane = tid & 63;
  const int wm = wave >> 2, wn = wave & 3;
  const int fr5 = lane & 31, h = lane >> 5;

  // 2D XCD chunking: 8 chunks of 8n x 16m tiles (~3MB working set / XCD L2)
  const int bid = blockIdx.x;
  const int xcd = bid & 7, idx = bid >> 3;
  const int nt = (xcd >> 1) * 8 + (idx >> 4);
  const int mt = (xcd & 1) * 16 + (idx & 15);
  const int n0 = nt * 256, m0 = mt * 256;

  const int aoff = (wm * 128 + fr5) * 64 + (((h << 1) ^ chunk_key(fr5)) << 4);

  const unsigned char* Bb = TfT + ((size_t)(m0 + wn * 64 + fr5)) * 64 + h * 32;
#define BK_T(kt) (Bb + (size_t)(kt) * (M_PTS * 64))

  // prologue: issue ALL 16 A-stage instrs (tiles 0..7 in order), then the
  // 8 B-prologue loads.
#pragma unroll
  for (int kt = 0; kt < 8; ++kt) {
    stgA(Xf, n0, kt * 64, lds8 + kt * 16384, tid);
    stgA(Xf, n0 + 128, kt * 64, lds8 + kt * 16384 + 8192, tid);
  }
  i32x8 s0[2], s1[2], s2[2];
  s0[0] = ld2x16(BK_T(0), BK_T(0) + 16);
  s0[1] = ld2x16(BK_T(0) + 2048, BK_T(0) + 2048 + 16);
  s1[0] = ld2x16(BK_T(1), BK_T(1) + 16);
  s1[1] = ld2x16(BK_T(1) + 2048, BK_T(1) + 2048 + 16);
  // 24 VMEM issued; vmcnt(16) => oldest 8 retired = tiles 0-3 staged.
  asm volatile("s_waitcnt vmcnt(16)" ::: "memory");
  BARRIER;

  f32x16 acc[4][2] = {};
  tile_nf<true>(lds8 + 0 * 16384, BK_T(2), aoff, s0, s2, acc);   // t0
  tile_nf<true>(lds8 + 1 * 16384, BK_T(3), aoff, s1, s0, acc);   // t1
  tile_nf<true>(lds8 + 2 * 16384, BK_T(4), aoff, s2, s1, acc);   // t2
  tile_nf<true>(lds8 + 3 * 16384, BK_T(5), aoff, s0, s2, acc);   // t3
  // 40 VMEM issued; vmcnt(24) => oldest 16 retired = ALL A stages done.
  asm volatile("s_waitcnt vmcnt(24)" ::: "memory");
  BARRIER;
  tile_nf<true>(lds8 + 4 * 16384, BK_T(6), aoff, s1, s0, acc);   // t4
  tile_nf<true>(lds8 + 5 * 16384, BK_T(7), aoff, s2, s1, acc);   // t5
  tile_nf<false>(lds8 + 6 * 16384, BK_T(7), aoff, s0, s2, acc);  // t6
  tile_nf<false>(lds8 + 7 * 16384, BK_T(7), aoff, s1, s2, acc);  // t7

  // Epilogue: v = phi_b[n] - dot; min over the wave's 128 rows per column.
  // 32x32 C/D layout (m74/m101): col = lane&31, row = (q&3)+8*(q>>2)+4*h
  float mv0 = 3.4e38f, mv1 = 3.4e38f;
#pragma unroll
  for (int i = 0; i < 4; ++i) {
    float pb[16];
#pragma unroll
    for (int q = 0; q < 16; ++q)
      pb[q] = phi_b[n0 + wm * 128 + i * 32 + (q & 3) + 8 * (q >> 2) + 4 * h];
#pragma unroll
    for (int q = 0; q < 16; ++q) {
      mv0 = fminf(mv0, pb[q] - acc[i][0][q]);
      mv1 = fminf(mv1, pb[q] - acc[i][1][q]);
    }
  }
  mv0 = fminf(mv0, __shfl_xor(mv0, 32));
  mv1 = fminf(mv1, __shfl_xor(mv1, 32));
  if (h == 0) {
    atomicMin(&keys[m0 + wn * 64 + fr5], fenc(mv0));
    atomicMin(&keys[m0 + wn * 64 + 32 + fr5], fenc(mv1));
  }
#undef BK_T
}

// =====================================================================
// Kernel 4: partial reduce — 64 blocks x 256 threads (unchanged).
// =====================================================================
__global__ __launch_bounds__(256)
void partial_kernel(const float* __restrict__ xsq, const float* __restrict__ phi_b,
                    const float* __restrict__ tsq, const unsigned* __restrict__ keys,
                    double* __restrict__ partials) {
  const int b = blockIdx.x, t = threadIdx.x;
  double s;
  if (b < 32) {
    const int n = b * 256 + t;
    s = 0.5 * (double)xsq[n] - (double)phi_b[n];
  } else {
    const int m = (b - 32) * 256 + t;
    s = 0.5 * (double)tsq[m] + (double)fdec(keys[m]);
  }
  const int lane = t & 63, wv = t >> 6;
#pragma unroll
  for (int k = 1; k <= 32; k <<= 1) s += __shfl_xor(s, k);
  __shared__ double ps[4];
  if (lane == 0) ps[wv] = s;
  __syncthreads();
  if (t == 0) partials[b] = ps[0] + ps[1] + ps[2] + ps[3];
}

// =====================================================================
// Kernel 5: final: sum 64 partials (fixed order), write scalar.
// =====================================================================
__global__ __launch_bounds__(64)
void final_kernel(const double* __restrict__ partials, float* __restrict__ out) {
  if (threadIdx.x == 0) {
    double a = 0.0, c = 0.0;
#pragma unroll
    for (int i = 0; i < 32; ++i) a += partials[i];
#pragma unroll
    for (int i = 32; i < 64; ++i) c += partials[i];
    out[0] = (float)(a / N_PTS + c / M_PTS);
  }
}

// =====================================================================
extern "C" void kernel_launch(void* const* d_in, const int* in_sizes, int n_in,
                              void* d_out, int out_size, void* d_ws, size_t ws_size,
                              hipStream_t stream) {
  const float* x = (const float*)d_in[0];
  const float* tgt = (const float*)d_in[1];
  const float* W = (const float*)d_in[2];

  char* ws = (char*)d_ws;
  const size_t XB_BYTES = (size_t)N_PTS * DIM * 2;   // bf16 x (for phi_b)
  const size_t XF_BYTES = (size_t)N_PTS * DIM;       // fp8 x (plain row order)
  const size_t TF_BYTES = (size_t)M_PTS * DIM;       // fp8 t (fragment-major)
  const size_t WT_BYTES = (size_t)KDIM * DIM * 2;
  unsigned short* Xb = (unsigned short*)ws;
  unsigned char* Xf8 = (unsigned char*)(ws + XB_BYTES);
  unsigned char* TfT = (unsigned char*)(ws + XB_BYTES + XF_BYTES);
  unsigned short* WbT = (unsigned short*)(ws + XB_BYTES + XF_BYTES + TF_BYTES);
  float* phi_b = (float*)(ws + XB_BYTES + XF_BYTES + TF_BYTES + WT_BYTES);
  float* xsq = phi_b + N_PTS;
  float* tsq = xsq + N_PTS;
  unsigned* keys = (unsigned*)(tsq + M_PTS);
  double* partials = (double*)(keys + M_PTS + 64);   // 8B-aligned region

  const int prep_blocks = (N_PTS + M_PTS) / 4 + (KDIM * DIM) / 256;
  prep_all_kernel<<<prep_blocks, 256, 0, stream>>>(x, tgt, W, Xb, Xf8, TfT, WbT,
                                                   xsq, tsq, keys);
  phi_b_kernel<<<N_PTS / 32, 256, 0, stream>>>((const short*)Xb, (const short*)WbT, phi_b);
  gemm_min_kernel<<<(N_PTS / 256) * (M_PTS / 256), 512, 0, stream>>>(Xf8, TfT, phi_b, keys);
  partial_kernel<<<64, 256, 0, stream>>>(xsq, phi_b, tsq, keys, partials);
  final_kernel<<<1, 64, 0, stream>>>(partials, (float*)d_out);
}

// Round 21
// 65.278 us; speedup vs baseline: 1.2140x; 1.0354x over previous
//
#include <hip/hip_runtime.h>
#include <hip/hip_bf16.h>
#include <stdint.h>

typedef __attribute__((ext_vector_type(8))) short short8;
typedef __attribute__((ext_vector_type(4))) float f32x4;
typedef __attribute__((ext_vector_type(16))) float f32x16;
typedef __attribute__((ext_vector_type(4))) int i32x4;
typedef __attribute__((ext_vector_type(8))) int i32x8;

#define N_PTS 8192
#define M_PTS 8192
#define DIM   512
#define KDIM  128

// ---- float <-> order-preserving uint key (for atomicMin on float) ----
__device__ __forceinline__ unsigned fenc(float f) {
  unsigned u = __float_as_uint(f);
  return (u & 0x80000000u) ? ~u : (u | 0x80000000u);
}
__device__ __forceinline__ float fdec(unsigned k) {
  unsigned u = (k & 0x80000000u) ? (k ^ 0x80000000u) : ~k;
  return __uint_as_float(u);
}

__device__ __forceinline__ unsigned short f2bf(float f) {
  union { __hip_bfloat16 h; unsigned short u; } c;
  c.h = __float2bfloat16(f);
  return c.u;
}

// ---- float -> OCP e4m3fn, RNE, flush |f|<2^-6 to 0 (x,t ~ N(0,1)) ----
__device__ __forceinline__ unsigned f2e4m3(float f) {
  unsigned u = __float_as_uint(f);
  unsigned s = (u >> 24) & 0x80;
  unsigned mag = u & 0x7fffffffu;
  unsigned r = mag + 0x0007ffffu + ((mag >> 20) & 1u);  // RNE to 3 mantissa bits
  int e = (int)(r >> 23) - 127;
  if (e < -6) return s;                                 // flush tiny to zero
  unsigned m = (r >> 20) & 7u;
  return s | (unsigned)((e + 7) << 3) | m;
}

// ---- async global -> LDS, 16B per lane ----
__device__ __forceinline__ void async_copy16(const void* g, void* l) {
  __builtin_amdgcn_global_load_lds(
      (const __attribute__((address_space(1))) void*)g,
      (__attribute__((address_space(3))) void*)l, 16, 0, 0);
}

// ---- bf16 LDS slot swizzle (proven 0-conflict geometry) ----
__device__ __forceinline__ int swz_slot(int row, int slot) {
  return slot ^ ((row >> 1) & 3);
}

// ---- A-tile chunk key (row bits 1..4; stage/read-consistent) ----
__device__ __forceinline__ int chunk_key(int row) {
  return ((row >> 1) & 3) ^ ((row >> 3) & 1) ^ (((row >> 4) & 1) << 1);
}

#define BARRIER __builtin_amdgcn_s_barrier()

// =====================================================================
// Kernel 1: prep-all. Blocks < 4096: one wave per row:
// x -> Xb(bf16) + Xf8(e4m3 plain rows) + xsq; target -> TfT (e4m3,
// fragment-major [kt][8192][64B]) + tsq + key init.
// Blocks >= 4096: W transpose-cast. Block 0 thread 0: zero the
// done-counter for the fused reduce kernel.
// =====================================================================
__global__ __launch_bounds__(256)
void prep_all_kernel(const float* __restrict__ x, const float* __restrict__ tgt,
                     const float* __restrict__ W,
                     unsigned short* __restrict__ Xb, unsigned char* __restrict__ Xf8,
                     unsigned char* __restrict__ TfT, unsigned short* __restrict__ WbT,
                     float* __restrict__ xsq, float* __restrict__ tsq,
                     unsigned* __restrict__ keys, unsigned* __restrict__ counter) {
  const int bid = blockIdx.x;
  const int tid = threadIdx.x;
  if (bid == 0 && tid == 0) *counter = 0u;
  if (bid >= (N_PTS + M_PTS) / 4) {
    const int o = (bid - (N_PTS + M_PTS) / 4) * 256 + tid;  // 0..65535
    const int k = o >> 9, d = o & 511;
    WbT[o] = f2bf(W[d * KDIM + k]);
    return;
  }
  const int gw = (bid * 256 + tid) >> 6;
  const int j = tid & 63;
  float s;
  if (gw < N_PTS) {
    const float* src = x + (size_t)gw * DIM + j * 8;
    float4 v0 = *(const float4*)src;
    float4 v1 = *(const float4*)(src + 4);
    s = v0.x * v0.x + v0.y * v0.y + v0.z * v0.z + v0.w * v0.w +
        v1.x * v1.x + v1.y * v1.y + v1.z * v1.z + v1.w * v1.w;
    unsigned short* db = Xb + (size_t)gw * DIM + j * 8;
    ushort4 ob0, ob1;
    ob0.x = f2bf(v0.x); ob0.y = f2bf(v0.y); ob0.z = f2bf(v0.z); ob0.w = f2bf(v0.w);
    ob1.x = f2bf(v1.x); ob1.y = f2bf(v1.y); ob1.z = f2bf(v1.z); ob1.w = f2bf(v1.w);
    *(ushort4*)db = ob0;
    *(ushort4*)(db + 4) = ob1;
    unsigned long long p = (unsigned long long)f2e4m3(v0.x)
        | ((unsigned long long)f2e4m3(v0.y) << 8)
        | ((unsigned long long)f2e4m3(v0.z) << 16)
        | ((unsigned long long)f2e4m3(v0.w) << 24)
        | ((unsigned long long)f2e4m3(v1.x) << 32)
        | ((unsigned long long)f2e4m3(v1.y) << 40)
        | ((unsigned long long)f2e4m3(v1.z) << 48)
        | ((unsigned long long)f2e4m3(v1.w) << 56);
    *(unsigned long long*)(Xf8 + (size_t)gw * DIM + j * 8) = p;
#pragma unroll
    for (int m = 1; m <= 32; m <<= 1) s += __shfl_xor(s, m);
    if (j == 0) xsq[gw] = s;
  } else {
    const int tr = gw - N_PTS;
    const float* src = tgt + (size_t)tr * DIM + j * 8;
    float4 v0 = *(const float4*)src;
    float4 v1 = *(const float4*)(src + 4);
    s = v0.x * v0.x + v0.y * v0.y + v0.z * v0.z + v0.w * v0.w +
        v1.x * v1.x + v1.y * v1.y + v1.z * v1.z + v1.w * v1.w;
    unsigned long long p = (unsigned long long)f2e4m3(v0.x)
        | ((unsigned long long)f2e4m3(v0.y) << 8)
        | ((unsigned long long)f2e4m3(v0.z) << 16)
        | ((unsigned long long)f2e4m3(v0.w) << 24)
        | ((unsigned long long)f2e4m3(v1.x) << 32)
        | ((unsigned long long)f2e4m3(v1.y) << 40)
        | ((unsigned long long)f2e4m3(v1.z) << 48)
        | ((unsigned long long)f2e4m3(v1.w) << 56);
    // fragment-major: [kt = j>>3][row tr][byte (j&7)*8]
    *(unsigned long long*)(TfT + ((size_t)(j >> 3) * M_PTS + tr) * 64 + (j & 7) * 8) = p;
#pragma unroll
    for (int m = 1; m <= 32; m <<= 1) s += __shfl_xor(s, m);
    if (j == 0) { tsq[tr] = s; keys[tr] = 0xFFFFFFFFu; }
  }
}

// =====================================================================
// Kernel 2: phi_b — 256 blocks x 32 rows (r16 retile, unchanged).
// =====================================================================
__global__ __launch_bounds__(256)
void phi_b_kernel(const short* __restrict__ Xb, const short* __restrict__ WbT,
                  float* __restrict__ phi_b) {
  __shared__ __align__(16) short As[32 * 32];
  __shared__ __align__(16) short Bs[128 * 32];
  __shared__ __align__(16) float lg[32][136];

  const int tid = threadIdx.x;
  const int wave = tid >> 6, lane = tid & 63;
  const int n0 = blockIdx.x * 32;
  const int fr = lane & 15, g = lane >> 4;
  const int wc = wave;

  const int srow = tid >> 2;
  const int sk8 = swz_slot(srow, tid & 3) * 8;
  const int ra = tid >> 2;
  const int ska = swz_slot(ra, tid & 3) * 8;

  f32x4 acc[2][2] = {};
  for (int kt = 0; kt < 16; ++kt) {
    const int k0 = kt * 32;
    if (wave < 2)
      async_copy16(Xb + (size_t)(n0 + ra) * DIM + k0 + ska, &As[wave * 512]);
    async_copy16(WbT + (size_t)srow * DIM + k0 + sk8, &Bs[wave * 512]);
    async_copy16(WbT + (size_t)(srow + 64) * DIM + k0 + sk8, &Bs[2048 + wave * 512]);
    __syncthreads();
    short8 a[2], b[2];
#pragma unroll
    for (int i = 0; i < 2; ++i) {
      const int R = i * 16 + fr;
      a[i] = *(const short8*)&As[R * 32 + swz_slot(R, g) * 8];
    }
#pragma unroll
    for (int jx = 0; jx < 2; ++jx) {
      const int R = wc * 32 + jx * 16 + fr;
      b[jx] = *(const short8*)&Bs[R * 32 + swz_slot(R, g) * 8];
    }
#pragma unroll
    for (int i = 0; i < 2; ++i)
#pragma unroll
      for (int jx = 0; jx < 2; ++jx)
        acc[i][jx] = __builtin_amdgcn_mfma_f32_16x16x32_bf16(a[i], b[jx], acc[i][jx], 0, 0, 0);
    __syncthreads();
  }

  const int rq = g * 4;
#pragma unroll
  for (int i = 0; i < 2; ++i)
#pragma unroll
    for (int jx = 0; jx < 2; ++jx)
#pragma unroll
      for (int q = 0; q < 4; ++q)
        lg[i * 16 + rq + q][wc * 32 + jx * 16 + fr] = acc[i][jx][q];
  __syncthreads();

  const int row = tid >> 3, c8 = tid & 7;
  const float4* lr = (const float4*)(&lg[row][c8 * 16]);
  float mx = -3.4e38f;
#pragma unroll
  for (int c = 0; c < 4; ++c) {
    float4 v = lr[c];
    mx = fmaxf(mx, fmaxf(fmaxf(v.x, v.y), fmaxf(v.z, v.w)));
  }
  mx = fmaxf(mx, __shfl_xor(mx, 1));
  mx = fmaxf(mx, __shfl_xor(mx, 2));
  mx = fmaxf(mx, __shfl_xor(mx, 4));
  float s = 0.f;
#pragma unroll
  for (int c = 0; c < 4; ++c) {
    float4 v = lr[c];
    s += __expf(v.x - mx) + __expf(v.y - mx) + __expf(v.z - mx) + __expf(v.w - mx);
  }
  s += __shfl_xor(s, 1);
  s += __shfl_xor(s, 2);
  s += __shfl_xor(s, 4);
  if (c8 == 0) phi_b[n0 + row] = mx + logf(s);
}

// =====================================================================
// Kernel 3: fused MX-fp8 GEMM + min epilogue — r20 winner (barrier-free
// K-loop, split prologue drain); setprio removed (T5 prereq absent in
// a phase-free schedule; m190 measured it slightly negative).
// =====================================================================
__device__ __forceinline__ void stgA(const unsigned char* __restrict__ mat,
                                     int rowbase, int kbyte,
                                     unsigned char* dst, int tid) {
  const int r = tid >> 2, d = tid & 3;
  async_copy16(mat + (size_t)(rowbase + r) * DIM + kbyte + ((d ^ chunk_key(r)) << 4),
               dst + (tid >> 6) * 1024);
}

__device__ __forceinline__ i32x8 ld2x16(const unsigned char* p0, const unsigned char* p1) {
  i32x4 lo = *(const i32x4*)p0;
  i32x4 hi = *(const i32x4*)p1;
  return __builtin_shufflevector(lo, hi, 0, 1, 2, 3, 4, 5, 6, 7);
}

__device__ __forceinline__ f32x16 mfma_mx(i32x8 a, i32x8 b, f32x16 c) {
  return __builtin_amdgcn_mfma_scale_f32_32x32x64_f8f6f4(a, b, c, 0, 0,
                                                         0, 0x7F, 0, 0x7F);
}

template <bool LDB>
__device__ __forceinline__ void tile_nf(const unsigned char* __restrict__ Abuf,
                                        const unsigned char* __restrict__ Bnx,
                                        int aoff, i32x8 (&fb)[2], i32x8 (&fbn)[2],
                                        f32x16 (&acc)[4][2]) {
  i32x8 fa[4];
#pragma unroll
  for (int i = 0; i < 4; ++i)
    fa[i] = ld2x16(Abuf + aoff + i * 2048, Abuf + ((aoff + i * 2048) ^ 16));
  if (LDB) {
    fbn[0] = ld2x16(Bnx, Bnx + 16);
    fbn[1] = ld2x16(Bnx + 2048, Bnx + 2048 + 16);
  }
#pragma unroll
  for (int i = 0; i < 4; ++i) acc[i][0] = mfma_mx(fa[i], fb[0], acc[i][0]);
#pragma unroll
  for (int i = 0; i < 4; ++i) acc[i][1] = mfma_mx(fa[i], fb[1], acc[i][1]);
}

__global__ __launch_bounds__(512, 1)
void gemm_min_kernel(const unsigned char* __restrict__ Xf, const unsigned char* __restrict__ TfT,
                     const float* __restrict__ phi_b, unsigned* __restrict__ keys) {
  __shared__ __align__(16) unsigned char lds8[131072];   // 8 x 16KB A tiles

  const int tid = threadIdx.x;
  const int wave = tid >> 6, lane = tid & 63;
  const int wm = wave >> 2, wn = wave & 3;
  const int fr5 = lane & 31, h = lane >> 5;

  // 2D XCD chunking: 8 chunks of 8n x 16m tiles (~3MB working set / XCD L2)
  const int bid = blockIdx.x;
  const int xcd = bid & 7, idx = bid >> 3;
  const int nt = (xcd >> 1) * 8 + (idx >> 4);
  const int mt = (xcd & 1) * 16 + (idx & 15);
  const int n0 = nt * 256, m0 = mt * 256;

  const int aoff = (wm * 128 + fr5) * 64 + (((h << 1) ^ chunk_key(fr5)) << 4);

  const unsigned char* Bb = TfT + ((size_t)(m0 + wn * 64 + fr5)) * 64 + h * 32;
#define BK_T(kt) (Bb + (size_t)(kt) * (M_PTS * 64))

  // prologue: issue all 16 A-stage instrs (tiles 0..7 in order), then
  // the 8 B-prologue loads; vmcnt(16) => tiles 0-3 staged (FIFO).
#pragma unroll
  for (int kt = 0; kt < 8; ++kt) {
    stgA(Xf, n0, kt * 64, lds8 + kt * 16384, tid);
    stgA(Xf, n0 + 128, kt * 64, lds8 + kt * 16384 + 8192, tid);
  }
  i32x8 s0[2], s1[2], s2[2];
  s0[0] = ld2x16(BK_T(0), BK_T(0) + 16);
  s0[1] = ld2x16(BK_T(0) + 2048, BK_T(0) + 2048 + 16);
  s1[0] = ld2x16(BK_T(1), BK_T(1) + 16);
  s1[1] = ld2x16(BK_T(1) + 2048, BK_T(1) + 2048 + 16);
  asm volatile("s_waitcnt vmcnt(16)" ::: "memory");
  BARRIER;

  f32x16 acc[4][2] = {};
  tile_nf<true>(lds8 + 0 * 16384, BK_T(2), aoff, s0, s2, acc);   // t0
  tile_nf<true>(lds8 + 1 * 16384, BK_T(3), aoff, s1, s0, acc);   // t1
  tile_nf<true>(lds8 + 2 * 16384, BK_T(4), aoff, s2, s1, acc);   // t2
  tile_nf<true>(lds8 + 3 * 16384, BK_T(5), aoff, s0, s2, acc);   // t3
  // 40 VMEM issued; vmcnt(24) => all 16 A stages retired.
  asm volatile("s_waitcnt vmcnt(24)" ::: "memory");
  BARRIER;
  tile_nf<true>(lds8 + 4 * 16384, BK_T(6), aoff, s1, s0, acc);   // t4
  tile_nf<true>(lds8 + 5 * 16384, BK_T(7), aoff, s2, s1, acc);   // t5
  tile_nf<false>(lds8 + 6 * 16384, BK_T(7), aoff, s0, s2, acc);  // t6
  tile_nf<false>(lds8 + 7 * 16384, BK_T(7), aoff, s1, s2, acc);  // t7

  // Epilogue: v = phi_b[n] - dot; min over the wave's 128 rows per column.
  // 32x32 C/D layout (m74/m101): col = lane&31, row = (q&3)+8*(q>>2)+4*h
  float mv0 = 3.4e38f, mv1 = 3.4e38f;
#pragma unroll
  for (int i = 0; i < 4; ++i) {
    float pb[16];
#pragma unroll
    for (int q = 0; q < 16; ++q)
      pb[q] = phi_b[n0 + wm * 128 + i * 32 + (q & 3) + 8 * (q >> 2) + 4 * h];
#pragma unroll
    for (int q = 0; q < 16; ++q) {
      mv0 = fminf(mv0, pb[q] - acc[i][0][q]);
      mv1 = fminf(mv1, pb[q] - acc[i][1][q]);
    }
  }
  mv0 = fminf(mv0, __shfl_xor(mv0, 32));
  mv1 = fminf(mv1, __shfl_xor(mv1, 32));
  if (h == 0) {
    atomicMin(&keys[m0 + wn * 64 + fr5], fenc(mv0));
    atomicMin(&keys[m0 + wn * 64 + 32 + fr5], fenc(mv1));
  }
#undef BK_T
}

// =====================================================================
// Kernel 4: FUSED reduce — 64 blocks x 256 threads; the last-finished
// block sums the 64 partials in fixed order and writes the scalar.
// Deterministic: per-block partials are fixed-tree; final sum is
// fixed-order over all 64 slots regardless of which block runs it.
// =====================================================================
__global__ __launch_bounds__(256)
void reduce_kernel(const float* __restrict__ xsq, const float* __restrict__ phi_b,
                   const float* __restrict__ tsq, const unsigned* __restrict__ keys,
                   double* __restrict__ partials, unsigned* __restrict__ counter,
                   float* __restrict__ out) {
  const int b = blockIdx.x, t = threadIdx.x;
  double s;
  if (b < 32) {
    const int n = b * 256 + t;
    s = 0.5 * (double)xsq[n] - (double)phi_b[n];
  } else {
    const int m = (b - 32) * 256 + t;
    s = 0.5 * (double)tsq[m] + (double)fdec(keys[m]);
  }
  const int lane = t & 63, wv = t >> 6;
#pragma unroll
  for (int k = 1; k <= 32; k <<= 1) s += __shfl_xor(s, k);
  __shared__ double ps[4];
  __shared__ bool last;
  if (lane == 0) ps[wv] = s;
  __syncthreads();
  if (t == 0) {
    partials[b] = ps[0] + ps[1] + ps[2] + ps[3];
    __threadfence();                          // publish partial (device scope)
    unsigned done = atomicAdd(counter, 1u);   // device-scope by default
    last = (done == 63u);
  }
  __syncthreads();
  if (last && t == 0) {
    __threadfence();                          // acquire others' partials
    double a = 0.0, c = 0.0;
#pragma unroll
    for (int i = 0; i < 32; ++i) a += partials[i];
#pragma unroll
    for (int i = 32; i < 64; ++i) c += partials[i];
    out[0] = (float)(a / N_PTS + c / M_PTS);
  }
}

// =====================================================================
extern "C" void kernel_launch(void* const* d_in, const int* in_sizes, int n_in,
                              void* d_out, int out_size, void* d_ws, size_t ws_size,
                              hipStream_t stream) {
  const float* x = (const float*)d_in[0];
  const float* tgt = (const float*)d_in[1];
  const float* W = (const float*)d_in[2];

  char* ws = (char*)d_ws;
  const size_t XB_BYTES = (size_t)N_PTS * DIM * 2;   // bf16 x (for phi_b)
  const size_t XF_BYTES = (size_t)N_PTS * DIM;       // fp8 x (plain row order)
  const size_t TF_BYTES = (size_t)M_PTS * DIM;       // fp8 t (fragment-major)
  const size_t WT_BYTES = (size_t)KDIM * DIM * 2;
  unsigned short* Xb = (unsigned short*)ws;
  unsigned char* Xf8 = (unsigned char*)(ws + XB_BYTES);
  unsigned char* TfT = (unsigned char*)(ws + XB_BYTES + XF_BYTES);
  unsigned short* WbT = (unsigned short*)(ws + XB_BYTES + XF_BYTES + TF_BYTES);
  float* phi_b = (float*)(ws + XB_BYTES + XF_BYTES + TF_BYTES + WT_BYTES);
  float* xsq = phi_b + N_PTS;
  float* tsq = xsq + N_PTS;
  unsigned* keys = (unsigned*)(tsq + M_PTS);
  double* partials = (double*)(keys + M_PTS + 64);   // 8B-aligned region
  unsigned* counter = (unsigned*)(partials + 64);

  const int prep_blocks = (N_PTS + M_PTS) / 4 + (KDIM * DIM) / 256;
  prep_all_kernel<<<prep_blocks, 256, 0, stream>>>(x, tgt, W, Xb, Xf8, TfT, WbT,
                                                   xsq, tsq, keys, counter);
  phi_b_kernel<<<N_PTS / 32, 256, 0, stream>>>((const short*)Xb, (const short*)WbT, phi_b);
  gemm_min_kernel<<<(N_PTS / 256) * (M_PTS / 256), 512, 0, stream>>>(Xf8, TfT, phi_b, keys);
  reduce_kernel<<<64, 256, 0, stream>>>(xsq, phi_b, tsq, keys, partials, counter,
                                        (float*)d_out);
}